// Round 1
// 158.246 us; speedup vs baseline: 1.0775x; 1.0775x over previous
//
#include <hip/hip_runtime.h>

// RSI replicating jax-CPU cumsum via XLA ReduceWindowRewriter(base_length=16):
//   pad e[0..NP) with trailing zeros to 8192; reshape [512,16]
//   level-0: each 16-tile scanned SEQUENTIALLY (naive small reduce_window,
//            acc = 0, then left-to-right RN adds)
//   tile sums (512) -> recursively same: [32,16] seq tiles -> sums (32) ->
//            [2,16] seq tiles -> sums (2) -> naive len-2 scan
//   unwind: each element gets ONE RN add of the finalized exclusive outer
//            offset (broadcast add), per level.
// Epilogue op-for-op IEEE f32 like the reference:
//   a = cs[o+w-1] - (o>=1 ? cs[o-1] : 0);  ag = a/w; al = b/w;
//   rs = (al!=0) ? ag/al : 0;  out = 1 - 1/(1+rs)
//
// R1 change (layout only, bit-identical): LDS tile stride padded 16 -> 17.
//   Old: CG[16*b + r] — bank = (16b+r)%32 takes 2 values over 64 lanes
//        => 32-way conflict on every phase-A write and phase-C RMW
//        (SQ_LDS_BANK_CONFLICT = 2.07e7 ≈ 38% of CU cycles).
//   New: CG[17*b + r] — 17 coprime to 32 => each bank hit exactly 2x per
//        wave (2-way is free on CDNA4). T0/S1 get the same pad (one word
//        per 16 entries) to kill B1's stride-16 16-way conflict.
//   LDS 74752 -> 78880 B, still 2 blocks/CU (<= 80 KiB).

constexpr int ROWS = 2048;
constexpr int COLS = 8192;
constexpr int NP   = COLS - 1;   // 8191 p-values; padded to 8192
constexpr int BT   = 256;
constexpr int TS   = 17;         // padded tile stride (16 data + 1 pad)

__global__ __launch_bounds__(BT, 1)
void rsi_rwr_kernel(const float* __restrict__ x,
                    const int* __restrict__ wsp,
                    float* __restrict__ out,
                    int outW)
{
    // level-0 scan values -> final cumsum, padded stride 17
    __shared__ float CG[512 * TS], CL[512 * TS];
    // level-0 tile sums / level-1 scan values, padded: idx k -> k + (k>>4)
    __shared__ float T0g[544], T0l[544];
    __shared__ float S1g[544], S1l[544];
    __shared__ float T1g[32],  T1l[32];    // level-1 tile sums (tiny, unpadded)
    __shared__ float S2g[32],  S2l[32];    // level-2 scan values
    __shared__ float T2g[2],   T2l[2];     // level-2 tile sums
    __shared__ float S3g[2],   S3l[2];     // level-3 scan (len 2, naive)

    const int row = blockIdx.x;
    const int t   = threadIdx.x;
    const int wm1 = *wsp - 1;              // 13
    const float wf = (float)wm1;

    const float* __restrict__ xr = x + (size_t)row * COLS;

    // ---- phase A: elements + level-0 sequential 16-tile scans
    for (int b = t; b < 512; b += BT) {
        const float4* xv = reinterpret_cast<const float4*>(xr + 16 * b);
        float xe[17];
        {
            float4 v0 = xv[0], v1 = xv[1], v2 = xv[2], v3 = xv[3];
            xe[0]=v0.x;  xe[1]=v0.y;  xe[2]=v0.z;  xe[3]=v0.w;
            xe[4]=v1.x;  xe[5]=v1.y;  xe[6]=v1.z;  xe[7]=v1.w;
            xe[8]=v2.x;  xe[9]=v2.y;  xe[10]=v2.z; xe[11]=v2.w;
            xe[12]=v3.x; xe[13]=v3.y; xe[14]=v3.z; xe[15]=v3.w;
        }
        xe[16] = (b < 511) ? xr[16 * b + 16] : 0.f;   // unused for j==NP

        float cg = 0.f, cl = 0.f;
        float* __restrict__ cgp = &CG[TS * b];
        float* __restrict__ clp = &CL[TS * b];
        for (int r = 0; r < 16; ++r) {
            const int j = 16 * b + r;
            float eg = 0.f, el = 0.f;
            if (j < NP) {
                const float prev = xe[r];
                const float nxt  = xe[r + 1];
                if (prev != 0.f) {
                    const float p = (nxt - prev) / prev;   // IEEE f32 div
                    eg = (p > 0.f) ?  p : 0.f;
                    el = (p < 0.f) ? -p : 0.f;
                }
            }
            cg = cg + eg;          // RN; trailing pad adds +0 (bit-neutral)
            cl = cl + el;
            cgp[r] = cg;           // bank (17b+r)%32: 2-way across wave -> free
            clp[r] = cl;
        }
        T0g[b + (b >> 4)] = cg;    // padded T0 index
        T0l[b + (b >> 4)] = cl;
    }
    __syncthreads();

    // ---- phase B1: level-1 sequential 16-tile scans over T0 (32 tiles)
    if (t < 32) {
        float cg = 0.f, cl = 0.f;
        for (int s = 0; s < 16; ++s) {
            const int k = TS * t + s;          // padded index of 16*t+s
            cg = cg + T0g[k];                  // bank (17t+s)%32: conflict-free
            cl = cl + T0l[k];
            S1g[k] = cg;
            S1l[k] = cl;
        }
        T1g[t] = cg; T1l[t] = cl;
    }
    __syncthreads();

    // ---- phase B2: level-2 sequential 16-tile scans over T1 (2 tiles)
    if (t < 2) {
        float cg = 0.f, cl = 0.f;
        for (int u = 0; u < 16; ++u) {
            cg = cg + T1g[16 * t + u];
            cl = cl + T1l[16 * t + u];
            S2g[16 * t + u] = cg;
            S2l[16 * t + u] = cl;
        }
        T2g[t] = cg; T2l[t] = cl;
    }
    __syncthreads();

    // ---- phase B3: level-3 naive scan of T2 (len 2 <= base)
    if (t == 0) {
        S3g[0] = T2g[0]; S3g[1] = T2g[0] + T2g[1];
        S3l[0] = T2l[0]; S3l[1] = T2l[0] + T2l[1];
    }
    __syncthreads();
    // finalize S2: tile d=1 gets exclusive offset S3[0]
    if (t >= 16 && t < 32) {
        const int k = t;                       // 16..31
        S2g[k] = S2g[k] + S3g[0];
        S2l[k] = S2l[k] + S3l[0];
    }
    __syncthreads();
    // finalize S1: tiles c>=1 get exclusive offset S2[c-1]
    for (int k = 16 + t; k < 512; k += BT) {
        const int c  = k >> 4;
        const int kp = k + (k >> 4);           // padded index
        S1g[kp] = S1g[kp] + S2g[c - 1];
        S1l[kp] = S1l[kp] + S2l[c - 1];
    }
    __syncthreads();

    // ---- phase C: element offsets: tiles b>=1 get exclusive offset S1[b-1]
    for (int b = t; b < 512; b += BT) {
        if (b >= 1) {
            const int bp = (b - 1) + ((b - 1) >> 4);
            const float og = S1g[bp], ol = S1l[bp];
            float* __restrict__ cgp = &CG[TS * b];
            float* __restrict__ clp = &CL[TS * b];
            for (int r = 0; r < 16; ++r) {
                cgp[r] = cgp[r] + og;          // single RN add; conflict-free
                clp[r] = clp[r] + ol;
            }
        }
    }
    __syncthreads();

    // ---- phase D: epilogue, op-for-op IEEE f32
    float* __restrict__ outr = out + (size_t)row * outW;
    for (int o = t; o < outW; o += BT) {
        const int j2 = o + wm1 - 1;
        const int i2 = TS * (j2 >> 4) + (j2 & 15);
        float cg1 = 0.f, cl1 = 0.f;
        if (o >= 1) {
            const int j1 = o - 1;
            const int i1 = TS * (j1 >> 4) + (j1 & 15);
            cg1 = CG[i1];
            cl1 = CL[i1];
        }
        const float a  = CG[i2] - cg1;
        const float bb = CL[i2] - cl1;
        const float ag = a / wf;
        const float al = bb / wf;
        const float rs = (al != 0.f) ? (ag / al) : 0.f;
        outr[o] = 1.f - 1.f / (1.f + rs);
    }
}

extern "C" void kernel_launch(void* const* d_in, const int* in_sizes, int n_in,
                              void* d_out, int out_size, void* d_ws, size_t ws_size,
                              hipStream_t stream) {
    const float* x   = (const float*)d_in[0];
    const int*   wsp = (const int*)d_in[1];
    float*       out = (float*)d_out;

    const int outW = out_size / ROWS;   // 8179
    dim3 grid(ROWS);                    // one block per row
    dim3 block(BT);
    rsi_rwr_kernel<<<grid, block, 0, stream>>>(x, wsp, out, outW);
}

// Round 2
// 137.575 us; speedup vs baseline: 1.2394x; 1.1503x over previous
//
#include <hip/hip_runtime.h>

// RSI replicating jax-CPU cumsum via XLA ReduceWindowRewriter(base_length=16):
//   pad e[0..NP) with trailing zeros to 8192; reshape [512,16]
//   level-0: each 16-tile scanned SEQUENTIALLY; tile sums (512) -> recursively
//   [32,16] -> (32) -> [2,16] -> (2) -> len-2 scan; unwind adds ONE RN
//   exclusive outer offset per level.
//
// R1: LDS tile stride 16 -> 17 (bank-conflict fix, 2.07e7 -> 2.33e6).
// R2 changes:
//   (a) level-0 scan values kept in REGISTERS (rg/rl[2][16]); phase A no
//       longer writes CG/CL, phase C becomes a single write (scan+offset,
//       same one RN add as before -> bit-identical cumsum). Element LDS
//       ops cut 320 -> 192 per thread.
//   (b) epilogue: rs = (a/w)/(b/w) replaced by rs = a*rcp(b), and
//       1/(1+rs) by rcp(1+rs). Errors are RELATIVE (<= ~3e-7 on out),
//       downstream of the windowed-difference cancellation, negligible
//       vs the 3.9e-3 cross-implementation absmax. Guard al!=0 <=> b!=0
//       holds exactly (b nonzero => b >= ulp of O(1..100) cumsum >> 13*2^-150).
//       Phase A's division stays IEEE-exact (upstream of cancellation).
//   (c) phase D incremental LDS indices: o += 256 => i += 272.

constexpr int ROWS = 2048;
constexpr int COLS = 8192;
constexpr int NP   = COLS - 1;   // 8191 p-values; padded to 8192
constexpr int BT   = 256;
constexpr int TS   = 17;         // padded tile stride (16 data + 1 pad)

__global__ __launch_bounds__(BT, 1)
void rsi_rwr_kernel(const float* __restrict__ x,
                    const int* __restrict__ wsp,
                    float* __restrict__ out,
                    int outW)
{
    // final cumsum (written once in phase C), padded stride 17
    __shared__ float CG[512 * TS], CL[512 * TS];
    // level-0 tile sums / level-1 scan values, padded: idx k -> k + (k>>4)
    __shared__ float T0g[544], T0l[544];
    __shared__ float S1g[544], S1l[544];
    __shared__ float T1g[32],  T1l[32];    // level-1 tile sums
    __shared__ float S2g[32],  S2l[32];    // level-2 scan values
    __shared__ float T2g[2],   T2l[2];     // level-2 tile sums
    __shared__ float S3g[2],   S3l[2];     // level-3 scan (len 2, naive)

    const int row = blockIdx.x;
    const int t   = threadIdx.x;
    const int wm1 = *wsp - 1;              // 13

    const float* __restrict__ xr = x + (size_t)row * COLS;

    // level-0 scan values live in registers until phase C
    float rg[2][16], rl[2][16];

    // ---- phase A: elements + level-0 sequential 16-tile scans (regs only)
    #pragma unroll
    for (int bi = 0; bi < 2; ++bi) {
        const int b = t + 256 * bi;        // < 512 by construction
        const float4* xv = reinterpret_cast<const float4*>(xr + 16 * b);
        float xe[17];
        {
            float4 v0 = xv[0], v1 = xv[1], v2 = xv[2], v3 = xv[3];
            xe[0]=v0.x;  xe[1]=v0.y;  xe[2]=v0.z;  xe[3]=v0.w;
            xe[4]=v1.x;  xe[5]=v1.y;  xe[6]=v1.z;  xe[7]=v1.w;
            xe[8]=v2.x;  xe[9]=v2.y;  xe[10]=v2.z; xe[11]=v2.w;
            xe[12]=v3.x; xe[13]=v3.y; xe[14]=v3.z; xe[15]=v3.w;
        }
        xe[16] = (b < 511) ? xr[16 * b + 16] : 0.f;   // unused for j==NP

        float cg = 0.f, cl = 0.f;
        #pragma unroll
        for (int r = 0; r < 16; ++r) {
            const int j = 16 * b + r;
            float eg = 0.f, el = 0.f;
            if (j < NP) {
                const float prev = xe[r];
                const float nxt  = xe[r + 1];
                if (prev != 0.f) {
                    const float p = (nxt - prev) / prev;   // IEEE f32 div (exact)
                    eg = (p > 0.f) ?  p : 0.f;
                    el = (p < 0.f) ? -p : 0.f;
                }
            }
            cg = cg + eg;          // RN; trailing pad adds +0 (bit-neutral)
            cl = cl + el;
            rg[bi][r] = cg;
            rl[bi][r] = cl;
        }
        T0g[b + (b >> 4)] = cg;    // padded T0 index
        T0l[b + (b >> 4)] = cl;
    }
    __syncthreads();

    // ---- phase B1: level-1 sequential 16-tile scans over T0 (32 tiles)
    if (t < 32) {
        float cg = 0.f, cl = 0.f;
        for (int s = 0; s < 16; ++s) {
            const int k = TS * t + s;          // padded index of 16*t+s
            cg = cg + T0g[k];
            cl = cl + T0l[k];
            S1g[k] = cg;
            S1l[k] = cl;
        }
        T1g[t] = cg; T1l[t] = cl;
    }
    __syncthreads();

    // ---- phase B2: level-2 sequential 16-tile scans over T1 (2 tiles)
    if (t < 2) {
        float cg = 0.f, cl = 0.f;
        for (int u = 0; u < 16; ++u) {
            cg = cg + T1g[16 * t + u];
            cl = cl + T1l[16 * t + u];
            S2g[16 * t + u] = cg;
            S2l[16 * t + u] = cl;
        }
        T2g[t] = cg; T2l[t] = cl;
    }
    __syncthreads();

    // ---- phase B3: level-3 naive scan of T2 (len 2 <= base)
    if (t == 0) {
        S3g[0] = T2g[0]; S3g[1] = T2g[0] + T2g[1];
        S3l[0] = T2l[0]; S3l[1] = T2l[0] + T2l[1];
    }
    __syncthreads();
    // finalize S2: tile d=1 gets exclusive offset S3[0]
    if (t >= 16 && t < 32) {
        const int k = t;                       // 16..31
        S2g[k] = S2g[k] + S3g[0];
        S2l[k] = S2l[k] + S3l[0];
    }
    __syncthreads();
    // finalize S1: tiles c>=1 get exclusive offset S2[c-1]
    for (int k = 16 + t; k < 512; k += BT) {
        const int c  = k >> 4;
        const int kp = k + (k >> 4);           // padded index
        S1g[kp] = S1g[kp] + S2g[c - 1];
        S1l[kp] = S1l[kp] + S2l[c - 1];
    }
    __syncthreads();

    // ---- phase C: write final cumsum = reg scan value + exclusive offset
    //      (single RN add, same op as before; b==0 adds +0.0 which is
    //       bit-neutral since all scan values are >= +0)
    #pragma unroll
    for (int bi = 0; bi < 2; ++bi) {
        const int b = t + 256 * bi;
        float og = 0.f, ol = 0.f;
        if (b >= 1) {
            const int bp = (b - 1) + ((b - 1) >> 4);
            og = S1g[bp]; ol = S1l[bp];
        }
        float* __restrict__ cgp = &CG[TS * b];
        float* __restrict__ clp = &CL[TS * b];
        #pragma unroll
        for (int r = 0; r < 16; ++r) {
            cgp[r] = rg[bi][r] + og;           // conflict-free (stride 17)
            clp[r] = rl[bi][r] + ol;
        }
    }
    __syncthreads();

    // ---- phase D: epilogue
    //   a  = cs_g[o+w-1] - (o>=1 ? cs_g[o-1] : 0)
    //   bb = cs_l[o+w-1] - (o>=1 ? cs_l[o-1] : 0)
    //   rs = (bb!=0) ? a*rcp(bb) : 0        ( == (a/w)/(bb/w) to ~2.4e-7 rel)
    //   out = 1 - rcp(1+rs)
    float* __restrict__ outr = out + (size_t)row * outW;
    {
        int o  = t;
        int j2 = o + wm1 - 1;
        int i2 = TS * (j2 >> 4) + (j2 & 15);
        // index of (o-1); for o==0 set so that +272 lands on index(255)=270
        int i1 = (o >= 1) ? (TS * ((o - 1) >> 4) + ((o - 1) & 15)) : -2;
        for (; o < outW; o += BT, i2 += 272, i1 += 272) {
            float cg1 = 0.f, cl1 = 0.f;
            if (o >= 1) {
                cg1 = CG[i1];
                cl1 = CL[i1];
            }
            const float a  = CG[i2] - cg1;
            const float bb = CL[i2] - cl1;
            float rs = 0.f;
            if (bb != 0.f) rs = a * __builtin_amdgcn_rcpf(bb);
            outr[o] = 1.f - __builtin_amdgcn_rcpf(1.f + rs);
        }
    }
}

extern "C" void kernel_launch(void* const* d_in, const int* in_sizes, int n_in,
                              void* d_out, int out_size, void* d_ws, size_t ws_size,
                              hipStream_t stream) {
    const float* x   = (const float*)d_in[0];
    const int*   wsp = (const int*)d_in[1];
    float*       out = (float*)d_out;

    const int outW = out_size / ROWS;   // 8179
    dim3 grid(ROWS);                    // one block per row
    dim3 block(BT);
    rsi_rwr_kernel<<<grid, block, 0, stream>>>(x, wsp, out, outW);
}